// Round 4
// baseline (744.157 us; speedup 1.0000x reference)
//
#include <hip/hip_runtime.h>
#include <math.h>

#define BLK 256  // 64 rows/block, 4 lanes per row

constexpr int PAR_CT[24] = {-1,0,0,0,1,2,3,4,5,6,7,8,9,9,9,12,13,14,16,17,18,19,20,21};

// broadcast staged float4 #M (owned by lane M&3, reg M>>2) to all 4 lanes of the quad
template<int M>
__device__ __forceinline__ float4 bcast_f4(const float4 (&s)[14]) {
    constexpr int lane = M & 3, reg = M >> 2;
    float4 v = s[reg], r;
    r.x = __shfl(v.x, lane, 4);
    r.y = __shfl(v.y, lane, 4);
    r.z = __shfl(v.z, lane, 4);
    r.w = __shfl(v.w, lane, 4);
    return r;
}

// broadcast jtr element #E from the 5-f4 stage
template<int E>
__device__ __forceinline__ float bcast_jt(const float4 (&s)[5]) {
    constexpr int m = E >> 2, lane = m & 3, reg = m >> 2, c = E & 3;
    float4 v = s[reg];
    float x = (c == 0) ? v.x : (c == 1) ? v.y : (c == 2) ? v.z : v.w;
    return __shfl(x, lane, 4);
}

struct JS {            // per-joint prepped state (rv windowed by off at use site)
    float rv[12];
    float jx, jy, jz, bl;
};

template<int J>
__device__ __forceinline__ void prep(const float4 (&rot_s)[14], const float4 (&jt_s)[5], JS& s)
{
    constexpr int P = PAR_CT[J];
    s.jx = bcast_jt<3*J+0>(jt_s);
    s.jy = bcast_jt<3*J+1>(jt_s);
    s.jz = bcast_jt<3*J+2>(jt_s);
    float dx, dy, dz;
    if constexpr (P < 0) { dx = s.jx; dy = s.jy; dz = s.jz; }
    else {
        const float px = bcast_jt<3*P+0>(jt_s);
        const float py = bcast_jt<3*P+1>(jt_s);
        const float pz = bcast_jt<3*P+2>(jt_s);
        dx = s.jx - px; dy = s.jy - py; dz = s.jz - pz;
    }
    s.bl = sqrtf(dx*dx + dy*dy + dz*dz);

    constexpr int w0 = (9*J) / 4;
    float4 A = bcast_f4<w0  >(rot_s);
    float4 B = bcast_f4<w0+1>(rot_s);
    float4 C = bcast_f4<w0+2>(rot_s);
    s.rv[0]=A.x; s.rv[1]=A.y; s.rv[2]=A.z; s.rv[3]=A.w;
    s.rv[4]=B.x; s.rv[5]=B.y; s.rv[6]=B.z; s.rv[7]=B.w;
    s.rv[8]=C.x; s.rv[9]=C.y; s.rv[10]=C.z; s.rv[11]=C.w;
}

template<int J>
__device__ __forceinline__ void l1row(const JS& s, const float (&gf)[6], const float (&o)[24][6],
                                      int u, int l, const float* __restrict__ W1s, float (&h)[5])
{
    constexpr int P   = PAR_CT[J];
    constexpr int off = (9*J) % 4;
    const int r = l + 4*u;
    if (r < 19) {
        const float* w = W1s + J*380 + r*20;   // [j][r][20], slot19 = b1
        float4 wa = *(const float4*)(w);
        float4 wb = *(const float4*)(w + 4);
        float4 wc = *(const float4*)(w + 8);
        float4 wd = *(const float4*)(w + 12);
        float4 we = *(const float4*)(w + 16);
        float acc = we.w;                      // b1[j][r]
        acc = fmaf(s.rv[off+0], wa.x, acc);
        acc = fmaf(s.rv[off+1], wa.y, acc);
        acc = fmaf(s.rv[off+2], wa.z, acc);
        acc = fmaf(s.rv[off+3], wa.w, acc);
        acc = fmaf(s.rv[off+4], wb.x, acc);
        acc = fmaf(s.rv[off+5], wb.y, acc);
        acc = fmaf(s.rv[off+6], wb.z, acc);
        acc = fmaf(s.rv[off+7], wb.w, acc);
        acc = fmaf(s.rv[off+8], wc.x, acc);
        acc = fmaf(s.jx, wc.y, acc);
        acc = fmaf(s.jy, wc.z, acc);
        acc = fmaf(s.jz, wc.w, acc);
        acc = fmaf(s.bl, wd.x, acc);
        if constexpr (P < 0) {
            acc = fmaf(gf[0], wd.y, acc);
            acc = fmaf(gf[1], wd.z, acc);
            acc = fmaf(gf[2], wd.w, acc);
            acc = fmaf(gf[3], we.x, acc);
            acc = fmaf(gf[4], we.y, acc);
            acc = fmaf(gf[5], we.z, acc);
        } else {
            acc = fmaf(o[P][0], wd.y, acc);
            acc = fmaf(o[P][1], wd.z, acc);
            acc = fmaf(o[P][2], wd.w, acc);
            acc = fmaf(o[P][3], we.x, acc);
            acc = fmaf(o[P][4], we.y, acc);
            acc = fmaf(o[P][5], we.z, acc);
        }
        h[u] = fmaxf(acc, 0.0f);
    }
}

template<int J>
__device__ __forceinline__ void l2row(const float (&h)[5], int u, int l,
                                      const float* __restrict__ W2s, float (&od)[6])
{
    const int r = l + 4*u;
    if (r < 19) {
        const float* w = W2s + J*152 + r*8;    // [j][r][8], pad 6,7
        float4 wa = *(const float4*)(w);
        float4 wb = *(const float4*)(w + 4);
        od[0] = fmaf(h[u], wa.x, od[0]);
        od[1] = fmaf(h[u], wa.y, od[1]);
        od[2] = fmaf(h[u], wa.z, od[2]);
        od[3] = fmaf(h[u], wa.w, od[3]);
        od[4] = fmaf(h[u], wb.x, od[4]);
        od[5] = fmaf(h[u], wb.y, od[5]);
    }
}

template<int J>
__device__ __forceinline__ void finishJ(float (&od)[6], const float* __restrict__ b2,
                                        float (&o)[24][6])
{
    #pragma unroll
    for (int d = 0; d < 6; ++d) {
        od[d] += __shfl_xor(od[d], 1, 4);
        od[d] += __shfl_xor(od[d], 2, 4);
        od[d] += b2[J*6 + d];                  // uniform -> s_load
        o[J][d] = od[d];
    }
}

template<int J>   // J odd: store pair (J-1, J) as 3x float4
__device__ __forceinline__ void store_pair(const float (&o)[24][6], float* __restrict__ orow, int l)
{
    static_assert(J & 1, "pair store at odd J");
    if (l < 3) {
        float4 v;
        if (l == 0)      { v.x = o[J-1][0]; v.y = o[J-1][1]; v.z = o[J-1][2]; v.w = o[J-1][3]; }
        else if (l == 1) { v.x = o[J-1][4]; v.y = o[J-1][5]; v.z = o[J][0];   v.w = o[J][1];   }
        else             { v.x = o[J][2];   v.y = o[J][3];   v.z = o[J][4];   v.w = o[J][5];   }
        *reinterpret_cast<float4*>(orow + (J-1)*6 + 4*l) = v;  // 16B-aligned
    }
}

// process up to 3 independent joints with layer loops interleaved across them
template<int JA, int JB, int JC>
__device__ __forceinline__ void group_step(const float4 (&rot_s)[14], const float4 (&jt_s)[5],
                                           const float* __restrict__ W1s,
                                           const float* __restrict__ W2s,
                                           const float* __restrict__ b2,
                                           const float (&gf)[6], float (&o)[24][6],
                                           float* __restrict__ orow, int l)
{
    JS sA, sB, sC;
    prep<JA>(rot_s, jt_s, sA);
    if constexpr (JB >= 0) prep<JB>(rot_s, jt_s, sB);
    if constexpr (JC >= 0) prep<JC>(rot_s, jt_s, sC);

    float hA[5], hB[5], hC[5];
    #pragma unroll
    for (int u = 0; u < 5; ++u) {
        l1row<JA>(sA, gf, o, u, l, W1s, hA);
        if constexpr (JB >= 0) l1row<JB>(sB, gf, o, u, l, W1s, hB);
        if constexpr (JC >= 0) l1row<JC>(sC, gf, o, u, l, W1s, hC);
    }

    float odA[6] = {0,0,0,0,0,0}, odB[6] = {0,0,0,0,0,0}, odC[6] = {0,0,0,0,0,0};
    #pragma unroll
    for (int u = 0; u < 5; ++u) {
        l2row<JA>(hA, u, l, W2s, odA);
        if constexpr (JB >= 0) l2row<JB>(hB, u, l, W2s, odB);
        if constexpr (JC >= 0) l2row<JC>(hC, u, l, W2s, odC);
    }

    finishJ<JA>(odA, b2, o);
    if constexpr (JB >= 0) finishJ<JB>(odB, b2, o);
    if constexpr (JC >= 0) finishJ<JC>(odC, b2, o);

    if constexpr (JA & 1) store_pair<JA>(o, orow, l);
    if constexpr (JB >= 0) { if constexpr (JB & 1) store_pair<JB>(o, orow, l); }
    if constexpr (JC >= 0) { if constexpr (JC & 1) store_pair<JC>(o, orow, l); }
}

__global__ __launch_bounds__(BLK, 3)
void pose_kernel(const float* __restrict__ rots,
                 const float* __restrict__ jtrs,
                 const float* __restrict__ W0,
                 const float* __restrict__ b0,
                 const float* __restrict__ W1,
                 const float* __restrict__ b1,
                 const float* __restrict__ W2,
                 const float* __restrict__ b2,
                 float* __restrict__ out,
                 int bsz)
{
    __shared__ __align__(16) float W1s[24*19*20];  // 36.48 KB, [j][r][20], slot19=b1
    __shared__ __align__(16) float W2s[24*19*8];   // 14.59 KB, [j][r][8], pad 6,7

    for (int idx = threadIdx.x; idx < 24*19*20; idx += BLK) {
        int j = idx / 380, rem = idx % 380, r = rem / 20, c = rem % 20;
        W1s[idx] = (c < 19) ? W1[(j*19 + r)*19 + c] : b1[j*19 + r];
    }
    for (int idx = threadIdx.x; idx < 24*19*8; idx += BLK) {
        int j = idx / 152, rem = idx % 152, r = rem / 8, d = rem % 8;
        W2s[idx] = (d < 6) ? W2[(j*6 + d)*19 + r] : 0.0f;   // transpose: [j][r][d]
    }
    __syncthreads();

    const int t   = blockIdx.x * BLK + threadIdx.x;
    const int row = t >> 2;
    const int l   = t & 3;
    if (row >= bsz) return;

    const float4* rp = reinterpret_cast<const float4*>(rots + (size_t)row * 216); // 54 f4
    const float4* jp = reinterpret_cast<const float4*>(jtrs + (size_t)row * 72);  // 18 f4
    float* orow = out + (size_t)row * 144;

    // ---- stage the whole row ONCE, coalesced (lane l owns f4 m=4i+l) ----
    float4 rot_s[14];
    #pragma unroll
    for (int i = 0; i < 13; ++i) rot_s[i] = rp[4*i + l];
    if (l < 2) rot_s[13] = rp[52 + l];

    float4 jt_s[5];
    #pragma unroll
    for (int i = 0; i < 4; ++i) jt_s[i] = jp[4*i + l];
    if (l < 2) jt_s[4] = jp[16 + l];

    // ---- gfeat from staged registers ----
    float gf[6] = {0,0,0,0,0,0};
    #pragma unroll
    for (int i = 0; i < 13; ++i) {
        const int m = 4*i + l;
        float4 v = rot_s[i];
        #pragma unroll
        for (int d = 0; d < 6; ++d) {
            float4 w = *reinterpret_cast<const float4*>(W0 + d*288 + 4*m);
            gf[d] = fmaf(v.x, w.x, gf[d]);
            gf[d] = fmaf(v.y, w.y, gf[d]);
            gf[d] = fmaf(v.z, w.z, gf[d]);
            gf[d] = fmaf(v.w, w.w, gf[d]);
        }
    }
    if (l < 2) {
        const int m = 52 + l;
        float4 v = rot_s[13];
        #pragma unroll
        for (int d = 0; d < 6; ++d) {
            float4 w = *reinterpret_cast<const float4*>(W0 + d*288 + 4*m);
            gf[d] = fmaf(v.x, w.x, gf[d]);
            gf[d] = fmaf(v.y, w.y, gf[d]);
            gf[d] = fmaf(v.z, w.z, gf[d]);
            gf[d] = fmaf(v.w, w.w, gf[d]);
        }
    }
    #pragma unroll
    for (int i = 0; i < 4; ++i) {
        const int m = 4*i + l;
        float4 v = jt_s[i];
        #pragma unroll
        for (int d = 0; d < 6; ++d) {
            float4 w = *reinterpret_cast<const float4*>(W0 + d*288 + 216 + 4*m);
            gf[d] = fmaf(v.x, w.x, gf[d]);
            gf[d] = fmaf(v.y, w.y, gf[d]);
            gf[d] = fmaf(v.z, w.z, gf[d]);
            gf[d] = fmaf(v.w, w.w, gf[d]);
        }
    }
    if (l < 2) {
        const int m = 16 + l;
        float4 v = jt_s[4];
        #pragma unroll
        for (int d = 0; d < 6; ++d) {
            float4 w = *reinterpret_cast<const float4*>(W0 + d*288 + 216 + 4*m);
            gf[d] = fmaf(v.x, w.x, gf[d]);
            gf[d] = fmaf(v.y, w.y, gf[d]);
            gf[d] = fmaf(v.z, w.z, gf[d]);
            gf[d] = fmaf(v.w, w.w, gf[d]);
        }
    }
    #pragma unroll
    for (int d = 0; d < 6; ++d) {
        gf[d] += __shfl_xor(gf[d], 1, 4);
        gf[d] += __shfl_xor(gf[d], 2, 4);
        gf[d] += b0[d];
    }

    // ---- joint chain by dependency level (<=3 independent joints interleaved) ----
    float o[24][6];
    group_step< 0,-1,-1>(rot_s, jt_s, W1s, W2s, b2, gf, o, orow, l);
    group_step< 1, 2, 3>(rot_s, jt_s, W1s, W2s, b2, gf, o, orow, l);
    group_step< 4, 5, 6>(rot_s, jt_s, W1s, W2s, b2, gf, o, orow, l);
    group_step< 7, 8, 9>(rot_s, jt_s, W1s, W2s, b2, gf, o, orow, l);
    group_step<10,11,12>(rot_s, jt_s, W1s, W2s, b2, gf, o, orow, l);
    group_step<13,14,-1>(rot_s, jt_s, W1s, W2s, b2, gf, o, orow, l);
    group_step<15,16,17>(rot_s, jt_s, W1s, W2s, b2, gf, o, orow, l);
    group_step<18,19,-1>(rot_s, jt_s, W1s, W2s, b2, gf, o, orow, l);
    group_step<20,21,-1>(rot_s, jt_s, W1s, W2s, b2, gf, o, orow, l);
    group_step<22,23,-1>(rot_s, jt_s, W1s, W2s, b2, gf, o, orow, l);
}

extern "C" void kernel_launch(void* const* d_in, const int* in_sizes, int n_in,
                              void* d_out, int out_size, void* d_ws, size_t ws_size,
                              hipStream_t stream)
{
    const float* rots = (const float*)d_in[0];
    const float* jtrs = (const float*)d_in[1];
    const float* W0   = (const float*)d_in[2];
    const float* b0   = (const float*)d_in[3];
    const float* W1   = (const float*)d_in[4];
    const float* b1   = (const float*)d_in[5];
    const float* W2   = (const float*)d_in[6];
    const float* b2   = (const float*)d_in[7];
    float* out = (float*)d_out;

    int bsz = in_sizes[0] / 216;
    long long threads = (long long)bsz * 4;
    int blocks = (int)((threads + BLK - 1) / BLK);
    hipLaunchKernelGGL(pose_kernel, dim3(blocks), dim3(BLK), 0, stream,
                       rots, jtrs, W0, b0, W1, b1, W2, b2, out, bsz);
}

// Round 5
// 321.299 us; speedup vs baseline: 2.3161x; 2.3161x over previous
//
#include <hip/hip_runtime.h>
#include <math.h>

#define BLK 256  // 64 rows/block, 4 lanes per row

constexpr int PAR_CT[24] = {-1,0,0,0,1,2,3,4,5,6,7,8,9,9,9,12,13,14,16,17,18,19,20,21};

// ---- DPP quad ops (VALU pipe — NOT ds_bpermute) ----
template<int CTRL>
__device__ __forceinline__ float dpp_f(float x) {
    return __int_as_float(__builtin_amdgcn_mov_dpp(__float_as_int(x), CTRL, 0xf, 0xf, true));
}
// broadcast lane Q of each quad: quad_perm [Q,Q,Q,Q] = Q*0x55
template<int Q> __device__ __forceinline__ float qbcast(float x) { return dpp_f<Q*0x55>(x); }
// xor within quad: [1,0,3,2]=0xB1, [2,3,0,1]=0x4E
__device__ __forceinline__ float qxor1(float x) { return dpp_f<0xB1>(x); }
__device__ __forceinline__ float qxor2(float x) { return dpp_f<0x4E>(x); }

// broadcast staged float4 #M (owned by lane M&3, reg M>>2) to all 4 lanes of the quad
template<int M>
__device__ __forceinline__ float4 bcast_f4(const float4 (&s)[14]) {
    constexpr int lane = M & 3, reg = M >> 2;
    float4 v = s[reg], r;
    r.x = qbcast<lane>(v.x);
    r.y = qbcast<lane>(v.y);
    r.z = qbcast<lane>(v.z);
    r.w = qbcast<lane>(v.w);
    return r;
}

// broadcast jtr element #E from the 5-f4 stage
template<int E>
__device__ __forceinline__ float bcast_jt(const float4 (&s)[5]) {
    constexpr int m = E >> 2, lane = m & 3, reg = m >> 2, c = E & 3;
    float4 v = s[reg];
    float x = (c == 0) ? v.x : (c == 1) ? v.y : (c == 2) ? v.z : v.w;
    return qbcast<lane>(x);
}

template<int J>
__device__ __forceinline__ void joint_step(const float4 (&rot_s)[14],
                                           const float4 (&jt_s)[5],
                                           const float* __restrict__ W1s,
                                           const float* __restrict__ W2s,
                                           const float* __restrict__ b2,
                                           const float (&gf)[6],
                                           float (&o)[24][6],
                                           float* __restrict__ orow,
                                           int l)
{
    constexpr int P = PAR_CT[J];

    // ---- jtr triples via DPP quad broadcast (VALU only) ----
    const float jx = bcast_jt<3*J+0>(jt_s);
    const float jy = bcast_jt<3*J+1>(jt_s);
    const float jz = bcast_jt<3*J+2>(jt_s);
    float dx, dy, dz;
    if constexpr (P < 0) { dx = jx; dy = jy; dz = jz; }
    else {
        const float px = bcast_jt<3*P+0>(jt_s);
        const float py = bcast_jt<3*P+1>(jt_s);
        const float pz = bcast_jt<3*P+2>(jt_s);
        dx = jx - px; dy = jy - py; dz = jz - pz;
    }
    const float bl = sqrtf(dx*dx + dy*dy + dz*dz);

    // ---- rot[9J..9J+8] via 3 DPP-broadcast f4s ----
    constexpr int w0  = (9*J) / 4;
    constexpr int off = (9*J) % 4;
    float4 A = bcast_f4<w0  >(rot_s);
    float4 B = bcast_f4<w0+1>(rot_s);
    float4 C = bcast_f4<w0+2>(rot_s);
    float rv[12] = {A.x,A.y,A.z,A.w, B.x,B.y,B.z,B.w, C.x,C.y,C.z,C.w};

    // ---- feat (replicated in all 4 lanes) ----
    float f0,f1,f2,f3,f4v,f5;
    if constexpr (P < 0) { f0=gf[0]; f1=gf[1]; f2=gf[2]; f3=gf[3]; f4v=gf[4]; f5=gf[5]; }
    else { f0=o[P][0]; f1=o[P][1]; f2=o[P][2]; f3=o[P][3]; f4v=o[P][4]; f5=o[P][5]; }

    // ---- layer 1: rows r = l + 4u; LDS reads are 4-addr + 16-lane broadcast ----
    float h[5];
    #pragma unroll
    for (int u = 0; u < 5; ++u) {
        const int r = l + 4*u;
        if (r < 19) {
            const float* w = W1s + J*380 + r*20;   // [j][r][20], slot19 = b1
            float4 wa = *(const float4*)(w);
            float4 wb = *(const float4*)(w + 4);
            float4 wc = *(const float4*)(w + 8);
            float4 wd = *(const float4*)(w + 12);
            float4 we = *(const float4*)(w + 16);
            float acc = we.w;                      // b1[j][r]
            acc = fmaf(rv[off+0], wa.x, acc);
            acc = fmaf(rv[off+1], wa.y, acc);
            acc = fmaf(rv[off+2], wa.z, acc);
            acc = fmaf(rv[off+3], wa.w, acc);
            acc = fmaf(rv[off+4], wb.x, acc);
            acc = fmaf(rv[off+5], wb.y, acc);
            acc = fmaf(rv[off+6], wb.z, acc);
            acc = fmaf(rv[off+7], wb.w, acc);
            acc = fmaf(rv[off+8], wc.x, acc);
            acc = fmaf(jx, wc.y, acc);
            acc = fmaf(jy, wc.z, acc);
            acc = fmaf(jz, wc.w, acc);
            acc = fmaf(bl, wd.x, acc);
            acc = fmaf(f0, wd.y, acc);
            acc = fmaf(f1, wd.z, acc);
            acc = fmaf(f2, wd.w, acc);
            acc = fmaf(f3, we.x, acc);
            acc = fmaf(f4v, we.y, acc);
            acc = fmaf(f5, we.z, acc);
            h[u] = fmaxf(acc, 0.0f);
        }
    }

    // ---- layer 2: W2s = [j][r][8] (pad), 2x b128 per row ----
    float od[6] = {0,0,0,0,0,0};
    #pragma unroll
    for (int u = 0; u < 5; ++u) {
        const int r = l + 4*u;
        if (r < 19) {
            const float* w = W2s + J*152 + r*8;
            float4 wa = *(const float4*)(w);
            float4 wb = *(const float4*)(w + 4);
            od[0] = fmaf(h[u], wa.x, od[0]);
            od[1] = fmaf(h[u], wa.y, od[1]);
            od[2] = fmaf(h[u], wa.z, od[2]);
            od[3] = fmaf(h[u], wa.w, od[3]);
            od[4] = fmaf(h[u], wb.x, od[4]);
            od[5] = fmaf(h[u], wb.y, od[5]);
        }
    }

    // ---- reduce across quad via DPP; add bias; all lanes get full o[J] ----
    #pragma unroll
    for (int d = 0; d < 6; ++d) {
        od[d] += qxor1(od[d]);
        od[d] += qxor2(od[d]);
        od[d] += b2[J*6 + d];                      // uniform -> s_load
        o[J][d] = od[d];
    }

    // ---- paired store: at odd J write o[J-1] (still live) + o[J] as 3x float4 ----
    if constexpr (J & 1) {
        if (l < 3) {
            float4 v;
            if (l == 0)      { v.x = o[J-1][0]; v.y = o[J-1][1]; v.z = o[J-1][2]; v.w = o[J-1][3]; }
            else if (l == 1) { v.x = o[J-1][4]; v.y = o[J-1][5]; v.z = o[J][0];   v.w = o[J][1];   }
            else             { v.x = o[J][2];   v.y = o[J][3];   v.z = o[J][4];   v.w = o[J][5];   }
            *reinterpret_cast<float4*>(orow + (J-1)*6 + 4*l) = v;  // 16B-aligned
        }
    }
}

template<int J>
__device__ __forceinline__ void run_chain(const float4 (&rot_s)[14],
                                          const float4 (&jt_s)[5],
                                          const float* __restrict__ W1s,
                                          const float* __restrict__ W2s,
                                          const float* __restrict__ b2,
                                          const float (&gf)[6],
                                          float (&o)[24][6],
                                          float* __restrict__ orow,
                                          int l)
{
    if constexpr (J < 24) {
        joint_step<J>(rot_s, jt_s, W1s, W2s, b2, gf, o, orow, l);
        run_chain<J+1>(rot_s, jt_s, W1s, W2s, b2, gf, o, orow, l);
    }
}

__global__ __launch_bounds__(BLK, 3)
void pose_kernel(const float* __restrict__ rots,
                 const float* __restrict__ jtrs,
                 const float* __restrict__ W0,
                 const float* __restrict__ b0,
                 const float* __restrict__ W1,
                 const float* __restrict__ b1,
                 const float* __restrict__ W2,
                 const float* __restrict__ b2,
                 float* __restrict__ out,
                 int bsz)
{
    __shared__ __align__(16) float W1s[24*19*20];  // 36.48 KB, [j][r][20], slot19=b1
    __shared__ __align__(16) float W2s[24*19*8];   // 14.59 KB, [j][r][8], pad 6,7

    for (int idx = threadIdx.x; idx < 24*19*20; idx += BLK) {
        int j = idx / 380, rem = idx % 380, r = rem / 20, c = rem % 20;
        W1s[idx] = (c < 19) ? W1[(j*19 + r)*19 + c] : b1[j*19 + r];
    }
    for (int idx = threadIdx.x; idx < 24*19*8; idx += BLK) {
        int j = idx / 152, rem = idx % 152, r = rem / 8, d = rem % 8;
        W2s[idx] = (d < 6) ? W2[(j*6 + d)*19 + r] : 0.0f;   // transpose: [j][r][d]
    }
    __syncthreads();

    const int t   = blockIdx.x * BLK + threadIdx.x;
    const int row = t >> 2;
    const int l   = t & 3;
    if (row >= bsz) return;

    const float4* rp = reinterpret_cast<const float4*>(rots + (size_t)row * 216); // 54 f4
    const float4* jp = reinterpret_cast<const float4*>(jtrs + (size_t)row * 72);  // 18 f4
    float* orow = out + (size_t)row * 144;

    // ---- stage the whole row ONCE, coalesced (lane l owns f4 m=4i+l) ----
    float4 rot_s[14];
    #pragma unroll
    for (int i = 0; i < 13; ++i) rot_s[i] = rp[4*i + l];
    if (l < 2) rot_s[13] = rp[52 + l];

    float4 jt_s[5];
    #pragma unroll
    for (int i = 0; i < 4; ++i) jt_s[i] = jp[4*i + l];
    if (l < 2) jt_s[4] = jp[16 + l];

    // ---- gfeat from staged registers ----
    float gf[6] = {0,0,0,0,0,0};
    #pragma unroll
    for (int i = 0; i < 13; ++i) {
        const int m = 4*i + l;
        float4 v = rot_s[i];
        #pragma unroll
        for (int d = 0; d < 6; ++d) {
            float4 w = *reinterpret_cast<const float4*>(W0 + d*288 + 4*m);
            gf[d] = fmaf(v.x, w.x, gf[d]);
            gf[d] = fmaf(v.y, w.y, gf[d]);
            gf[d] = fmaf(v.z, w.z, gf[d]);
            gf[d] = fmaf(v.w, w.w, gf[d]);
        }
    }
    if (l < 2) {
        const int m = 52 + l;
        float4 v = rot_s[13];
        #pragma unroll
        for (int d = 0; d < 6; ++d) {
            float4 w = *reinterpret_cast<const float4*>(W0 + d*288 + 4*m);
            gf[d] = fmaf(v.x, w.x, gf[d]);
            gf[d] = fmaf(v.y, w.y, gf[d]);
            gf[d] = fmaf(v.z, w.z, gf[d]);
            gf[d] = fmaf(v.w, w.w, gf[d]);
        }
    }
    #pragma unroll
    for (int i = 0; i < 4; ++i) {
        const int m = 4*i + l;
        float4 v = jt_s[i];
        #pragma unroll
        for (int d = 0; d < 6; ++d) {
            float4 w = *reinterpret_cast<const float4*>(W0 + d*288 + 216 + 4*m);
            gf[d] = fmaf(v.x, w.x, gf[d]);
            gf[d] = fmaf(v.y, w.y, gf[d]);
            gf[d] = fmaf(v.z, w.z, gf[d]);
            gf[d] = fmaf(v.w, w.w, gf[d]);
        }
    }
    if (l < 2) {
        const int m = 16 + l;
        float4 v = jt_s[4];
        #pragma unroll
        for (int d = 0; d < 6; ++d) {
            float4 w = *reinterpret_cast<const float4*>(W0 + d*288 + 216 + 4*m);
            gf[d] = fmaf(v.x, w.x, gf[d]);
            gf[d] = fmaf(v.y, w.y, gf[d]);
            gf[d] = fmaf(v.z, w.z, gf[d]);
            gf[d] = fmaf(v.w, w.w, gf[d]);
        }
    }
    #pragma unroll
    for (int d = 0; d < 6; ++d) {
        gf[d] += qxor1(gf[d]);
        gf[d] += qxor2(gf[d]);
        gf[d] += b0[d];
    }

    // ---- sequential 24-joint chain (registers + LDS weight-broadcast + DPP) ----
    float o[24][6];
    run_chain<0>(rot_s, jt_s, W1s, W2s, b2, gf, o, orow, l);
}

extern "C" void kernel_launch(void* const* d_in, const int* in_sizes, int n_in,
                              void* d_out, int out_size, void* d_ws, size_t ws_size,
                              hipStream_t stream)
{
    const float* rots = (const float*)d_in[0];
    const float* jtrs = (const float*)d_in[1];
    const float* W0   = (const float*)d_in[2];
    const float* b0   = (const float*)d_in[3];
    const float* W1   = (const float*)d_in[4];
    const float* b1   = (const float*)d_in[5];
    const float* W2   = (const float*)d_in[6];
    const float* b2   = (const float*)d_in[7];
    float* out = (float*)d_out;

    int bsz = in_sizes[0] / 216;
    long long threads = (long long)bsz * 4;
    int blocks = (int)((threads + BLK - 1) / BLK);
    hipLaunchKernelGGL(pose_kernel, dim3(blocks), dim3(BLK), 0, stream,
                       rots, jtrs, W0, b0, W1, b1, W2, b2, out, bsz);
}

// Round 6
// 320.305 us; speedup vs baseline: 2.3233x; 1.0031x over previous
//
#include <hip/hip_runtime.h>
#include <math.h>

#define BLK 256  // 64 quads/block, each quad = 2 batch rows, 4 lanes

constexpr int PAR_CT[24] = {-1,0,0,0,1,2,3,4,5,6,7,8,9,9,9,12,13,14,16,17,18,19,20,21};

// ---- DPP quad ops (VALU pipe) ----
template<int CTRL>
__device__ __forceinline__ float dpp_f(float x) {
    return __int_as_float(__builtin_amdgcn_mov_dpp(__float_as_int(x), CTRL, 0xf, 0xf, true));
}
template<int Q> __device__ __forceinline__ float qbcast(float x) { return dpp_f<Q*0x55>(x); }
__device__ __forceinline__ float qxor1(float x) { return dpp_f<0xB1>(x); }
__device__ __forceinline__ float qxor2(float x) { return dpp_f<0x4E>(x); }

template<int M>
__device__ __forceinline__ float4 bcast_f4(const float4 (&s)[14]) {
    constexpr int lane = M & 3, reg = M >> 2;
    float4 v = s[reg], r;
    r.x = qbcast<lane>(v.x);
    r.y = qbcast<lane>(v.y);
    r.z = qbcast<lane>(v.z);
    r.w = qbcast<lane>(v.w);
    return r;
}

template<int E>
__device__ __forceinline__ float bcast_jt(const float4 (&s)[5]) {
    constexpr int m = E >> 2, lane = m & 3, reg = m >> 2, c = E & 3;
    float4 v = s[reg];
    float x = (c == 0) ? v.x : (c == 1) ? v.y : (c == 2) ? v.z : v.w;
    return qbcast<lane>(x);
}

// per-row prepped joint state
struct JS { float rv[12]; float jx, jy, jz, bl; };

template<int J>
__device__ __forceinline__ void prep(const float4 (&rot_s)[14], const float4 (&jt_s)[5], JS& s)
{
    constexpr int P = PAR_CT[J];
    s.jx = bcast_jt<3*J+0>(jt_s);
    s.jy = bcast_jt<3*J+1>(jt_s);
    s.jz = bcast_jt<3*J+2>(jt_s);
    float dx, dy, dz;
    if constexpr (P < 0) { dx = s.jx; dy = s.jy; dz = s.jz; }
    else {
        const float px = bcast_jt<3*P+0>(jt_s);
        const float py = bcast_jt<3*P+1>(jt_s);
        const float pz = bcast_jt<3*P+2>(jt_s);
        dx = s.jx - px; dy = s.jy - py; dz = s.jz - pz;
    }
    s.bl = sqrtf(dx*dx + dy*dy + dz*dz);
    constexpr int w0 = (9*J) / 4;
    float4 A = bcast_f4<w0  >(rot_s);
    float4 B = bcast_f4<w0+1>(rot_s);
    float4 C = bcast_f4<w0+2>(rot_s);
    s.rv[0]=A.x; s.rv[1]=A.y; s.rv[2]=A.z; s.rv[3]=A.w;
    s.rv[4]=B.x; s.rv[5]=B.y; s.rv[6]=B.z; s.rv[7]=B.w;
    s.rv[8]=C.x; s.rv[9]=C.y; s.rv[10]=C.z; s.rv[11]=C.w;
}

// one layer-1 accumulation given already-loaded weight f4s
template<int J>
__device__ __forceinline__ float l1acc(const JS& s, const float (&gf)[6], const float (&o)[24][6],
                                       float4 wa, float4 wb, float4 wc, float4 wd, float4 we)
{
    constexpr int P   = PAR_CT[J];
    constexpr int off = (9*J) % 4;
    float acc = we.w;                          // b1[j][r]
    acc = fmaf(s.rv[off+0], wa.x, acc);
    acc = fmaf(s.rv[off+1], wa.y, acc);
    acc = fmaf(s.rv[off+2], wa.z, acc);
    acc = fmaf(s.rv[off+3], wa.w, acc);
    acc = fmaf(s.rv[off+4], wb.x, acc);
    acc = fmaf(s.rv[off+5], wb.y, acc);
    acc = fmaf(s.rv[off+6], wb.z, acc);
    acc = fmaf(s.rv[off+7], wb.w, acc);
    acc = fmaf(s.rv[off+8], wc.x, acc);
    acc = fmaf(s.jx, wc.y, acc);
    acc = fmaf(s.jy, wc.z, acc);
    acc = fmaf(s.jz, wc.w, acc);
    acc = fmaf(s.bl, wd.x, acc);
    if constexpr (P < 0) {
        acc = fmaf(gf[0], wd.y, acc);
        acc = fmaf(gf[1], wd.z, acc);
        acc = fmaf(gf[2], wd.w, acc);
        acc = fmaf(gf[3], we.x, acc);
        acc = fmaf(gf[4], we.y, acc);
        acc = fmaf(gf[5], we.z, acc);
    } else {
        acc = fmaf(o[P][0], wd.y, acc);
        acc = fmaf(o[P][1], wd.z, acc);
        acc = fmaf(o[P][2], wd.w, acc);
        acc = fmaf(o[P][3], we.x, acc);
        acc = fmaf(o[P][4], we.y, acc);
        acc = fmaf(o[P][5], we.z, acc);
    }
    return fmaxf(acc, 0.0f);
}

template<int J>
__device__ __forceinline__ void finishJ(float (&od)[6], const float* __restrict__ b2,
                                        float (&o)[24][6])
{
    #pragma unroll
    for (int d = 0; d < 6; ++d) {
        od[d] += qxor1(od[d]);
        od[d] += qxor2(od[d]);
        od[d] += b2[J*6 + d];                  // uniform -> s_load
        o[J][d] = od[d];
    }
}

template<int J>   // J odd: store pair (J-1, J) as 3x float4
__device__ __forceinline__ void store_pair(const float (&o)[24][6], float* __restrict__ orow, int l)
{
    static_assert(J & 1, "pair store at odd J");
    if (l < 3) {
        float4 v;
        if (l == 0)      { v.x = o[J-1][0]; v.y = o[J-1][1]; v.z = o[J-1][2]; v.w = o[J-1][3]; }
        else if (l == 1) { v.x = o[J-1][4]; v.y = o[J-1][5]; v.z = o[J][0];   v.w = o[J][1];   }
        else             { v.x = o[J][2];   v.y = o[J][3];   v.z = o[J][4];   v.w = o[J][5];   }
        *reinterpret_cast<float4*>(orow + (J-1)*6 + 4*l) = v;  // 16B-aligned
    }
}

// process joint J for BOTH rows, sharing every weight load
template<int J>
__device__ __forceinline__ void joint_step2(const float4 (&rotA)[14], const float4 (&jtA)[5],
                                            const float4 (&rotB)[14], const float4 (&jtB)[5],
                                            const float* __restrict__ W1s,
                                            const float* __restrict__ W2s,
                                            const float* __restrict__ b2,
                                            const float (&gfA)[6], const float (&gfB)[6],
                                            float (&oA)[24][6], float (&oB)[24][6],
                                            float* __restrict__ orowA, float* __restrict__ orowB,
                                            int l, bool hasB)
{
    JS sA, sB;
    prep<J>(rotA, jtA, sA);
    prep<J>(rotB, jtB, sB);

    float hA[5], hB[5];
    #pragma unroll
    for (int u = 0; u < 5; ++u) {
        const int r = l + 4*u;
        if (r < 19) {
            const float* w = W1s + J*380 + r*20;   // [j][r][20], slot19 = b1
            float4 wa = *(const float4*)(w);
            float4 wb = *(const float4*)(w + 4);
            float4 wc = *(const float4*)(w + 8);
            float4 wd = *(const float4*)(w + 12);
            float4 we = *(const float4*)(w + 16);
            hA[u] = l1acc<J>(sA, gfA, oA, wa, wb, wc, wd, we);
            hB[u] = l1acc<J>(sB, gfB, oB, wa, wb, wc, wd, we);
        }
    }

    float odA[6] = {0,0,0,0,0,0}, odB[6] = {0,0,0,0,0,0};
    #pragma unroll
    for (int u = 0; u < 5; ++u) {
        const int r = l + 4*u;
        if (r < 19) {
            const float* w = W2s + J*152 + r*8;    // [j][r][8]
            float4 wa = *(const float4*)(w);
            float4 wb = *(const float4*)(w + 4);
            odA[0] = fmaf(hA[u], wa.x, odA[0]);
            odA[1] = fmaf(hA[u], wa.y, odA[1]);
            odA[2] = fmaf(hA[u], wa.z, odA[2]);
            odA[3] = fmaf(hA[u], wa.w, odA[3]);
            odA[4] = fmaf(hA[u], wb.x, odA[4]);
            odA[5] = fmaf(hA[u], wb.y, odA[5]);
            odB[0] = fmaf(hB[u], wa.x, odB[0]);
            odB[1] = fmaf(hB[u], wa.y, odB[1]);
            odB[2] = fmaf(hB[u], wa.z, odB[2]);
            odB[3] = fmaf(hB[u], wa.w, odB[3]);
            odB[4] = fmaf(hB[u], wb.x, odB[4]);
            odB[5] = fmaf(hB[u], wb.y, odB[5]);
        }
    }

    finishJ<J>(odA, b2, oA);
    finishJ<J>(odB, b2, oB);

    if constexpr (J & 1) {
        store_pair<J>(oA, orowA, l);
        if (hasB) store_pair<J>(oB, orowB, l);
    }
}

template<int J>
__device__ __forceinline__ void run_chain2(const float4 (&rotA)[14], const float4 (&jtA)[5],
                                           const float4 (&rotB)[14], const float4 (&jtB)[5],
                                           const float* __restrict__ W1s,
                                           const float* __restrict__ W2s,
                                           const float* __restrict__ b2,
                                           const float (&gfA)[6], const float (&gfB)[6],
                                           float (&oA)[24][6], float (&oB)[24][6],
                                           float* __restrict__ orowA, float* __restrict__ orowB,
                                           int l, bool hasB)
{
    if constexpr (J < 24) {
        joint_step2<J>(rotA, jtA, rotB, jtB, W1s, W2s, b2, gfA, gfB, oA, oB, orowA, orowB, l, hasB);
        run_chain2<J+1>(rotA, jtA, rotB, jtB, W1s, W2s, b2, gfA, gfB, oA, oB, orowA, orowB, l, hasB);
    }
}

__global__ __launch_bounds__(BLK, 2)
void pose_kernel(const float* __restrict__ rots,
                 const float* __restrict__ jtrs,
                 const float* __restrict__ W0,
                 const float* __restrict__ b0,
                 const float* __restrict__ W1,
                 const float* __restrict__ b1,
                 const float* __restrict__ W2,
                 const float* __restrict__ b2,
                 float* __restrict__ out,
                 int bsz)
{
    __shared__ __align__(16) float W1s[24*19*20];  // 36.48 KB, slot19=b1
    __shared__ __align__(16) float W2s[24*19*8];   // 14.59 KB, [j][r][8]

    for (int idx = threadIdx.x; idx < 24*19*20; idx += BLK) {
        int j = idx / 380, rem = idx % 380, r = rem / 20, c = rem % 20;
        W1s[idx] = (c < 19) ? W1[(j*19 + r)*19 + c] : b1[j*19 + r];
    }
    for (int idx = threadIdx.x; idx < 24*19*8; idx += BLK) {
        int j = idx / 152, rem = idx % 152, r = rem / 8, d = rem % 8;
        W2s[idx] = (d < 6) ? W2[(j*6 + d)*19 + r] : 0.0f;
    }
    __syncthreads();

    const int t    = blockIdx.x * BLK + threadIdx.x;
    const int q    = t >> 2;
    const int l    = t & 3;
    const int rowA = 2*q;
    const int rowB = 2*q + 1;
    if (rowA >= bsz) return;
    const bool hasB = (rowB < bsz);

    const float4* rpA = reinterpret_cast<const float4*>(rots + (size_t)rowA * 216);
    const float4* jpA = reinterpret_cast<const float4*>(jtrs + (size_t)rowA * 72);
    const float4* rpB = reinterpret_cast<const float4*>(rots + (size_t)rowB * 216);
    const float4* jpB = reinterpret_cast<const float4*>(jtrs + (size_t)rowB * 72);
    float* orowA = out + (size_t)rowA * 144;
    float* orowB = out + (size_t)rowB * 144;

    // ---- stage both rows ONCE, coalesced within the quad ----
    float4 rotA[14], rotB[14], jtA[5], jtB[5];
    #pragma unroll
    for (int i = 0; i < 13; ++i) rotA[i] = rpA[4*i + l];
    if (l < 2) rotA[13] = rpA[52 + l];
    #pragma unroll
    for (int i = 0; i < 4; ++i) jtA[i] = jpA[4*i + l];
    if (l < 2) jtA[4] = jpA[16 + l];

    if (hasB) {
        #pragma unroll
        for (int i = 0; i < 13; ++i) rotB[i] = rpB[4*i + l];
        if (l < 2) rotB[13] = rpB[52 + l];
        #pragma unroll
        for (int i = 0; i < 4; ++i) jtB[i] = jpB[4*i + l];
        if (l < 2) jtB[4] = jpB[16 + l];
    } else {
        #pragma unroll
        for (int i = 0; i < 14; ++i) rotB[i] = make_float4(0,0,0,0);
        #pragma unroll
        for (int i = 0; i < 5; ++i)  jtB[i] = make_float4(0,0,0,0);
    }

    // ---- gfeat for both rows, W0 loads shared ----
    float gfA[6] = {0,0,0,0,0,0}, gfB[6] = {0,0,0,0,0,0};
    #pragma unroll
    for (int i = 0; i < 13; ++i) {
        const int m = 4*i + l;
        float4 vA = rotA[i], vB = rotB[i];
        #pragma unroll
        for (int d = 0; d < 6; ++d) {
            float4 w = *reinterpret_cast<const float4*>(W0 + d*288 + 4*m);
            gfA[d] = fmaf(vA.x, w.x, gfA[d]);
            gfA[d] = fmaf(vA.y, w.y, gfA[d]);
            gfA[d] = fmaf(vA.z, w.z, gfA[d]);
            gfA[d] = fmaf(vA.w, w.w, gfA[d]);
            gfB[d] = fmaf(vB.x, w.x, gfB[d]);
            gfB[d] = fmaf(vB.y, w.y, gfB[d]);
            gfB[d] = fmaf(vB.z, w.z, gfB[d]);
            gfB[d] = fmaf(vB.w, w.w, gfB[d]);
        }
    }
    if (l < 2) {
        const int m = 52 + l;
        float4 vA = rotA[13], vB = rotB[13];
        #pragma unroll
        for (int d = 0; d < 6; ++d) {
            float4 w = *reinterpret_cast<const float4*>(W0 + d*288 + 4*m);
            gfA[d] = fmaf(vA.x, w.x, gfA[d]);
            gfA[d] = fmaf(vA.y, w.y, gfA[d]);
            gfA[d] = fmaf(vA.z, w.z, gfA[d]);
            gfA[d] = fmaf(vA.w, w.w, gfA[d]);
            gfB[d] = fmaf(vB.x, w.x, gfB[d]);
            gfB[d] = fmaf(vB.y, w.y, gfB[d]);
            gfB[d] = fmaf(vB.z, w.z, gfB[d]);
            gfB[d] = fmaf(vB.w, w.w, gfB[d]);
        }
    }
    #pragma unroll
    for (int i = 0; i < 4; ++i) {
        const int m = 4*i + l;
        float4 vA = jtA[i], vB = jtB[i];
        #pragma unroll
        for (int d = 0; d < 6; ++d) {
            float4 w = *reinterpret_cast<const float4*>(W0 + d*288 + 216 + 4*m);
            gfA[d] = fmaf(vA.x, w.x, gfA[d]);
            gfA[d] = fmaf(vA.y, w.y, gfA[d]);
            gfA[d] = fmaf(vA.z, w.z, gfA[d]);
            gfA[d] = fmaf(vA.w, w.w, gfA[d]);
            gfB[d] = fmaf(vB.x, w.x, gfB[d]);
            gfB[d] = fmaf(vB.y, w.y, gfB[d]);
            gfB[d] = fmaf(vB.z, w.z, gfB[d]);
            gfB[d] = fmaf(vB.w, w.w, gfB[d]);
        }
    }
    if (l < 2) {
        const int m = 16 + l;
        float4 vA = jtA[4], vB = jtB[4];
        #pragma unroll
        for (int d = 0; d < 6; ++d) {
            float4 w = *reinterpret_cast<const float4*>(W0 + d*288 + 216 + 4*m);
            gfA[d] = fmaf(vA.x, w.x, gfA[d]);
            gfA[d] = fmaf(vA.y, w.y, gfA[d]);
            gfA[d] = fmaf(vA.z, w.z, gfA[d]);
            gfA[d] = fmaf(vA.w, w.w, gfA[d]);
            gfB[d] = fmaf(vB.x, w.x, gfB[d]);
            gfB[d] = fmaf(vB.y, w.y, gfB[d]);
            gfB[d] = fmaf(vB.z, w.z, gfB[d]);
            gfB[d] = fmaf(vB.w, w.w, gfB[d]);
        }
    }
    #pragma unroll
    for (int d = 0; d < 6; ++d) {
        gfA[d] += qxor1(gfA[d]);
        gfA[d] += qxor2(gfA[d]);
        gfA[d] += b0[d];
        gfB[d] += qxor1(gfB[d]);
        gfB[d] += qxor2(gfB[d]);
        gfB[d] += b0[d];
    }

    // ---- sequential 24-joint chain, both rows, shared weight loads ----
    float oA[24][6], oB[24][6];
    run_chain2<0>(rotA, jtA, rotB, jtB, W1s, W2s, b2, gfA, gfB, oA, oB, orowA, orowB, l, hasB);
}

extern "C" void kernel_launch(void* const* d_in, const int* in_sizes, int n_in,
                              void* d_out, int out_size, void* d_ws, size_t ws_size,
                              hipStream_t stream)
{
    const float* rots = (const float*)d_in[0];
    const float* jtrs = (const float*)d_in[1];
    const float* W0   = (const float*)d_in[2];
    const float* b0   = (const float*)d_in[3];
    const float* W1   = (const float*)d_in[4];
    const float* b1   = (const float*)d_in[5];
    const float* W2   = (const float*)d_in[6];
    const float* b2   = (const float*)d_in[7];
    float* out = (float*)d_out;

    int bsz = in_sizes[0] / 216;
    long long quads   = ((long long)bsz + 1) / 2;
    long long threads = quads * 4;
    int blocks = (int)((threads + BLK - 1) / BLK);
    hipLaunchKernelGGL(pose_kernel, dim3(blocks), dim3(BLK), 0, stream,
                       rots, jtrs, W0, b0, W1, b1, W2, b2, out, bsz);
}